// Round 8
// baseline (179.764 us; speedup 1.0000x reference)
//
#include <hip/hip_runtime.h>

typedef __attribute__((ext_vector_type(8))) short bf16x8;
typedef __attribute__((ext_vector_type(4))) float f32x4;
typedef __attribute__((ext_vector_type(4))) unsigned int u32x4;
typedef __attribute__((ext_vector_type(4))) unsigned short u16x4;

#define H_ 16
#define B_ 2
#define T_ 2048
#define DH_ 64
#define MD_ 1024

static __device__ inline unsigned short f2bf(float f) {  // round-nearest-even
    union { float f; unsigned u; } x; x.f = f;
    unsigned r = (x.u + 0x7fffu + ((x.u >> 16) & 1u)) >> 16;
    return (unsigned short)r;
}
// pack two fp32 -> two bf16 (truncation), lo in low short. 1 v_perm_b32.
static __device__ inline unsigned int pack_bf2(float lo, float hi) {
    return __builtin_amdgcn_perm(__float_as_uint(hi), __float_as_uint(lo), 0x07060302u);
}
static __device__ inline unsigned short hi16(float f) {
    return (unsigned short)(__float_as_uint(f) >> 16);
}

// ---------------------------------------------------------------------------
// Kernel 1: prep. blocks 0..1023: Wo fp32->bf16 (RNE). 1024..2047: K fp32->bf16
// (trunc, same layout). 2048..3071: V fp32 -> V^T bf16 [hb][dh][T] via LDS.
// ---------------------------------------------------------------------------
__global__ __launch_bounds__(256) void prep_k(const float* __restrict__ k,
                                              const float* __restrict__ v,
                                              const float* __restrict__ w,
                                              unsigned short* __restrict__ kb,
                                              unsigned short* __restrict__ vtb,
                                              unsigned short* __restrict__ wob) {
    __shared__ __attribute__((aligned(16))) unsigned short vt64[64][64];
    const int blk = blockIdx.x;
    const int tid = threadIdx.x;
    if (blk < 1024) {
        int i = (blk * 256 + tid) * 4;
        f32x4 x = *(const f32x4*)(w + i);
        u16x4 y;
        y[0] = f2bf(x[0]); y[1] = f2bf(x[1]); y[2] = f2bf(x[2]); y[3] = f2bf(x[3]);
        *(u16x4*)(wob + i) = y;
    } else if (blk < 2048) {
        int j = blk - 1024;
        const int hb = j >> 5, s0 = (j & 31) * 64;
        const int row = tid >> 2, c = (tid & 3) * 16;
        const long off = (long)hb * (T_ * DH_) + (long)(s0 + row) * DH_ + c;
        const float* p = k + off;
        f32x4 a0 = *(const f32x4*)p;
        f32x4 a1 = *(const f32x4*)(p + 4);
        f32x4 a2 = *(const f32x4*)(p + 8);
        f32x4 a3 = *(const f32x4*)(p + 12);
        u32x4 w0, w1;
        w0[0] = pack_bf2(a0[0], a0[1]); w0[1] = pack_bf2(a0[2], a0[3]);
        w0[2] = pack_bf2(a1[0], a1[1]); w0[3] = pack_bf2(a1[2], a1[3]);
        w1[0] = pack_bf2(a2[0], a2[1]); w1[1] = pack_bf2(a2[2], a2[3]);
        w1[2] = pack_bf2(a3[0], a3[1]); w1[3] = pack_bf2(a3[2], a3[3]);
        *(u32x4*)(kb + off) = w0;
        *(u32x4*)(kb + off + 8) = w1;
    } else {
        int j = blk - 2048;
        const int hb = j >> 5, s0 = (j & 31) * 64;
        const int vkp = tid & 31, vdg = tid >> 5;  // key-pair, dh-group
        const float* vp = v + (long)hb * (T_ * DH_) + (long)(s0 + 2 * vkp) * DH_ + vdg * 8;
        f32x4 va0 = *(const f32x4*)vp;
        f32x4 va1 = *(const f32x4*)(vp + 4);
        f32x4 vb0 = *(const f32x4*)(vp + DH_);
        f32x4 vb1 = *(const f32x4*)(vp + DH_ + 4);
#pragma unroll
        for (int jj = 0; jj < 4; jj++) {
            ((unsigned int*)&vt64[vdg * 8 + jj][0])[vkp]     = pack_bf2(va0[jj], vb0[jj]);
            ((unsigned int*)&vt64[vdg * 8 + 4 + jj][0])[vkp] = pack_bf2(va1[jj], vb1[jj]);
        }
        __syncthreads();
        const int dh = tid >> 2, kc = (tid & 3) * 16;
        u32x4 o0 = *(const u32x4*)&vt64[dh][kc];
        u32x4 o1 = *(const u32x4*)&vt64[dh][kc + 8];
        unsigned short* op = vtb + (long)hb * (DH_ * T_) + (long)dh * T_ + s0 + kc;
        *(u32x4*)op = o0;
        *(u32x4*)(op + 8) = o1;
    }
}

// ---------------------------------------------------------------------------
// Kernel 2: causal attention, KEY-split waves (unchanged from R7; the R7
// failure was merge_k under-coverage, not this kernel). Job = (hb, t, parity
// j); stages 128 keys (two 64-key groups) per iteration; wave w owns 32 local
// keys and computes QK^T/PV for all 64 q rows (Q in registers). Cross-wave
// O/l reduction via fp32 LDS exchange at job end. Partials to ws.
// ---------------------------------------------------------------------------
__global__ __launch_bounds__(256, 2) void attn_k(const float* __restrict__ q,
                                                 const unsigned short* __restrict__ kb,
                                                 const unsigned short* __restrict__ vtb,
                                                 unsigned short* __restrict__ pbuf,
                                                 float* __restrict__ lbuf) {
    const int bl = blockIdx.x;
    const int t = 31 - (bl >> 6);             // longest jobs dispatched first
    const int inner = bl & 63;
    const int hb = inner >> 1, j = inner & 1;
    const int tid = threadIdx.x;
    const int w = tid >> 6, lane = tid & 63;
    const int ln = lane & 15, quad = lane >> 4;

    __shared__ __attribute__((aligned(16))) unsigned short kt[128][72];   // [lkey][dh]
    __shared__ __attribute__((aligned(16))) unsigned short vt[64][136];   // [dh][lkey]
    __shared__ __attribute__((aligned(16))) unsigned short pl[4][64][40]; // per-wave P
    __shared__ float cl[2][64];

    const long kbase = (long)hb * (T_ * DH_);
    const long vbase = (long)hb * (DH_ * T_);
    const int nsteps = t + 1;
    const int qrow0 = t * 64;

    bf16x8 ones;
#pragma unroll
    for (int z = 0; z < 8; z++) ones[z] = (short)0x3F80;

    // Q fragments for ALL 64 rows, in registers (RNE, 1/sqrt(64) folded)
    bf16x8 qf[4][2];
#pragma unroll
    for (int qt = 0; qt < 4; qt++)
#pragma unroll
        for (int h = 0; h < 2; h++) {
            const float* qp = q + kbase + (long)(qrow0 + qt * 16 + ln) * DH_ + h * 32 + quad * 8;
            f32x4 a0 = *(const f32x4*)qp;
            f32x4 a1 = *(const f32x4*)(qp + 4);
#pragma unroll
            for (int z = 0; z < 4; z++) {
                qf[qt][h][z]     = (short)f2bf(a0[z] * 0.125f);
                qf[qt][h][4 + z] = (short)f2bf(a1[z] * 0.125f);
            }
        }

    f32x4 oacc[4][4];   // [qt][dt], key-slice partial
#pragma unroll
    for (int a = 0; a < 4; a++)
#pragma unroll
        for (int c = 0; c < 4; c++) oacc[a][c] = f32x4{0.f, 0.f, 0.f, 0.f};
    f32x4 lacc[4];
#pragma unroll
    for (int a = 0; a < 4; a++) lacc[a] = f32x4{0.f, 0.f, 0.f, 0.f};

    // staging geometry: kt: 2 rows' halves per thread; vt: 32 cols per thread
    const int krow = tid >> 1, kcol = (tid & 1) * 32;   // krow 0..127
    const int kgrp = krow >> 6, klr = krow & 63;
    const int vrow = tid >> 2, vcol = (tid & 3) * 32;   // vrow 0..63
    const int vgrp = vcol >> 6, vlc = vcol & 63;

    u32x4 kr[4], vr[4];
    auto prefetch = [&](int gA, int gB) {
        const int kg = kgrp ? gB : gA;
        const unsigned short* kp = kb + kbase + (long)(kg * 64 + klr) * DH_ + kcol;
#pragma unroll
        for (int z = 0; z < 4; z++) kr[z] = *(const u32x4*)(kp + z * 8);
        const int vg = vgrp ? gB : gA;
        const unsigned short* vp = vtb + vbase + (long)vrow * T_ + vg * 64 + vlc;
#pragma unroll
        for (int z = 0; z < 4; z++) vr[z] = *(const u32x4*)(vp + z * 8);
    };

    if (j < nsteps) prefetch(j, (j + 2 < nsteps) ? j + 2 : j);

#pragma unroll 1
    for (int sg = j; sg < nsteps; sg += 4) {
        const bool hasB = (sg + 2 < nsteps);
        const int sgB = hasB ? sg + 2 : sg;
        __syncthreads();
#pragma unroll
        for (int z = 0; z < 4; z++) *(u32x4*)&kt[krow][kcol + z * 8] = kr[z];
#pragma unroll
        for (int z = 0; z < 4; z++) *(u32x4*)&vt[vrow][vcol + z * 8] = vr[z];
        __syncthreads();

        if (sg + 4 < nsteps) prefetch(sg + 4, (sg + 6 < nsteps) ? sg + 6 : sg + 4);

        const int na = hasB ? 4 : 2;
        if (w < na) {
            const int g_w = (w < 2) ? sg : sgB;
            const int keybase = g_w * 64 + (w & 1) * 32;   // global key of local col 0
            const int krb = w * 32;                        // kt row base

            // QK^T: B-frags from kt (per-wave distinct rows), A = Q regs
            bf16x8 kf[2][2];
#pragma unroll
            for (int ks = 0; ks < 2; ks++)
#pragma unroll
                for (int h = 0; h < 2; h++)
                    kf[ks][h] = *(const bf16x8*)&kt[krb + ks * 16 + ln][h * 32 + quad * 8];
            f32x4 sa[4][2];
#pragma unroll
            for (int qt = 0; qt < 4; qt++)
#pragma unroll
                for (int ks = 0; ks < 2; ks++) {
                    f32x4 a = f32x4{0.f, 0.f, 0.f, 0.f};
                    a = __builtin_amdgcn_mfma_f32_16x16x32_bf16(qf[qt][0], kf[ks][0], a, 0, 0, 0);
                    a = __builtin_amdgcn_mfma_f32_16x16x32_bf16(qf[qt][1], kf[ks][1], a, 0, 0, 0);
                    sa[qt][ks] = a;
                }

            // p = exp(s) (+ causal mask when this wave's group is the diagonal)
            if (g_w == t) {
#pragma unroll
                for (int qt = 0; qt < 4; qt++)
#pragma unroll
                    for (int ks = 0; ks < 2; ks++) {
                        const int colg = keybase + ks * 16 + ln;
#pragma unroll
                        for (int r = 0; r < 4; r++) {
                            float p = __expf(sa[qt][ks][r]);
                            if (colg > qrow0 + qt * 16 + quad * 4 + r) p = 0.f;
                            pl[w][qt * 16 + quad * 4 + r][ks * 16 + ln] = hi16(p);
                        }
                    }
            } else {
#pragma unroll
                for (int qt = 0; qt < 4; qt++)
#pragma unroll
                    for (int ks = 0; ks < 2; ks++)
#pragma unroll
                        for (int r = 0; r < 4; r++)
                            pl[w][qt * 16 + quad * 4 + r][ks * 16 + ln] =
                                hi16(__expf(sa[qt][ks][r]));
            }

            // P A-frags (b128, in-wave LDS ordering) + V B-frags -> PV, l
            bf16x8 pf[4];
#pragma unroll
            for (int qt = 0; qt < 4; qt++)
                pf[qt] = *(const bf16x8*)&pl[w][qt * 16 + ln][quad * 8];
            bf16x8 vf[4];
#pragma unroll
            for (int dt = 0; dt < 4; dt++)
                vf[dt] = *(const bf16x8*)&vt[dt * 16 + ln][w * 32 + quad * 8];
#pragma unroll
            for (int qt = 0; qt < 4; qt++)
                lacc[qt] = __builtin_amdgcn_mfma_f32_16x16x32_bf16(pf[qt], ones, lacc[qt], 0, 0, 0);
#pragma unroll
            for (int qt = 0; qt < 4; qt++)
#pragma unroll
                for (int dt = 0; dt < 4; dt++)
                    oacc[qt][dt] = __builtin_amdgcn_mfma_f32_16x16x32_bf16(pf[qt], vf[dt], oacc[qt][dt], 0, 0, 0);
        }
    }

    // cross-wave reduction: fp32 exchange through dead kt (w1) / vt (w3) space
    float* ex0 = (float*)&kt[0][0];   // 4096 floats = 16 KB <= 18 KB
    float* ex1 = (float*)&vt[0][0];   // 4096 floats = 16 KB <= 17 KB
    __syncthreads();
    if (w == 1 || w == 3) {
        float* dst = (w == 1) ? ex0 : ex1;
#pragma unroll
        for (int qt = 0; qt < 4; qt++)
#pragma unroll
            for (int dt = 0; dt < 4; dt++)
#pragma unroll
                for (int r = 0; r < 4; r++)
                    dst[(qt * 16 + quad * 4 + r) * 64 + dt * 16 + ln] = oacc[qt][dt][r];
        if (ln == 0) {
#pragma unroll
            for (int qt = 0; qt < 4; qt++)
#pragma unroll
                for (int r = 0; r < 4; r++)
                    cl[w >> 1][qt * 16 + quad * 4 + r] = lacc[qt][r];
        }
    }
    __syncthreads();
    if (w == 0 || w == 2) {
        const float* src = (w == 0) ? ex0 : ex1;
#pragma unroll
        for (int qt = 0; qt < 4; qt++) {
#pragma unroll
            for (int dt = 0; dt < 4; dt++)
#pragma unroll
                for (int r = 0; r < 4; r++)
                    oacc[qt][dt][r] += src[(qt * 16 + quad * 4 + r) * 64 + dt * 16 + ln];
#pragma unroll
            for (int r = 0; r < 4; r++)
                lacc[qt][r] += cl[w >> 1][qt * 16 + quad * 4 + r];
        }
    }
    __syncthreads();
    if (w == 2) {
#pragma unroll
        for (int qt = 0; qt < 4; qt++)
#pragma unroll
            for (int dt = 0; dt < 4; dt++)
#pragma unroll
                for (int r = 0; r < 4; r++)
                    ex0[(qt * 16 + quad * 4 + r) * 64 + dt * 16 + ln] = oacc[qt][dt][r];
        if (ln == 0) {
#pragma unroll
            for (int qt = 0; qt < 4; qt++)
#pragma unroll
                for (int r = 0; r < 4; r++)
                    cl[0][qt * 16 + quad * 4 + r] = lacc[qt][r];
        }
    }
    __syncthreads();
    if (w == 0) {
        const int jb = (hb * 32 + t) * 2 + j;
        unsigned short* op = pbuf + (long)jb * 4096;
#pragma unroll
        for (int qt = 0; qt < 4; qt++) {
#pragma unroll
            for (int dt = 0; dt < 4; dt++)
#pragma unroll
                for (int r = 0; r < 4; r++) {
                    float o = oacc[qt][dt][r] +
                              ex0[(qt * 16 + quad * 4 + r) * 64 + dt * 16 + ln];
                    op[(qt * 16 + quad * 4 + r) * 64 + dt * 16 + ln] = hi16(o);
                }
            if (ln == 0) {
#pragma unroll
                for (int r = 0; r < 4; r++)
                    lbuf[jb * 64 + qt * 16 + quad * 4 + r] =
                        lacc[qt][r] + cl[0][qt * 16 + quad * 4 + r];
            }
        }
    }
}

// ---------------------------------------------------------------------------
// Kernel 3: merge the two parity partials -> ctx bf16 [4096][1024] (RNE).
// FIXED (R7 bug): each thread now merges its FULL 16-short chunk (two u32x4
// per partial), so all of ctx is written. 262144 threads x 16 shorts = 4M.
// ---------------------------------------------------------------------------
__global__ __launch_bounds__(256) void merge_k(const unsigned short* __restrict__ pbuf,
                                               const float* __restrict__ lbuf,
                                               unsigned short* __restrict__ ctx) {
    const int g = blockIdx.x * 256 + threadIdx.x;  // 0..262143
    const int dchunk = g & 3;                      // 16-short chunk within 64
    const int h = (g >> 2) & 15;
    const int m = g >> 6;                          // 0..4095
    const int b = m >> 11, tt = m & 2047;
    const int tl = tt >> 6, r64 = tt & 63;
    const int hb = h * 2 + b;
    const int jb = (hb * 32 + tl) * 2;
    const unsigned short* p0 = pbuf + (long)jb * 4096 + r64 * 64 + dchunk * 16;
    const unsigned short* p1 = p0 + 4096;
    const float l = lbuf[jb * 64 + r64] + lbuf[jb * 64 + 64 + r64];
    const float rl = __builtin_amdgcn_rcpf(l);
    unsigned short* cp = ctx + (long)m * MD_ + h * 64 + dchunk * 16;
#pragma unroll
    for (int half = 0; half < 2; half++) {
        u32x4 a = *(const u32x4*)(p0 + half * 8);
        u32x4 c = *(const u32x4*)(p1 + half * 8);
        u32x4 o;
#pragma unroll
        for (int z = 0; z < 4; z++) {
            float lo = (__uint_as_float(a[z] << 16) + __uint_as_float(c[z] << 16)) * rl;
            float hi = (__uint_as_float(a[z] & 0xffff0000u) + __uint_as_float(c[z] & 0xffff0000u)) * rl;
            o[z] = (unsigned)f2bf(lo) | ((unsigned)f2bf(hi) << 16);
        }
        *(u32x4*)(cp + half * 8) = o;
    }
}

// ---------------------------------------------------------------------------
// Kernel 4: projection GEMM. out[m][n] = ctx[m][:] . Wo[n][:] + bias[n]
// M=4096 N=1024 K=1024. BM=64 BN=64 BK=128 -> 1024 blocks (4/CU).
// XCD m-slicing: each XCD owns 512 m-rows (1 MB ctx) + full Wo (2 MB) in L2.
// ---------------------------------------------------------------------------
__global__ __launch_bounds__(256, 4) void proj_k(const unsigned short* __restrict__ A,
                                                 const unsigned short* __restrict__ Bw,
                                                 const float* __restrict__ bias,
                                                 float* __restrict__ out) {
    const int i = blockIdx.x;
    const int xcd = i & 7, rr = i >> 3;
    const int m0 = xcd * 512 + (rr >> 4) * 64;
    const int n0 = (rr & 15) * 64;
    const int tid = threadIdx.x;
    const int wave = tid >> 6, lane = tid & 63;
    const int wm = wave >> 1, wn = wave & 1;
    const int ln = lane & 15, quad = lane >> 4;

    __shared__ __attribute__((aligned(16))) unsigned short As[64][136];
    __shared__ __attribute__((aligned(16))) unsigned short Bs[64][136];

    const int srow = tid >> 2, sc = (tid & 3) * 32;

    f32x4 acc[2][2];
#pragma unroll
    for (int a = 0; a < 2; a++)
#pragma unroll
        for (int c = 0; c < 2; c++) acc[a][c] = f32x4{0.f, 0.f, 0.f, 0.f};

    u32x4 ar[4], br[4];
    {
        const unsigned short* ap = A + (long)(m0 + srow) * 1024 + sc;
        const unsigned short* bp = Bw + (long)(n0 + srow) * 1024 + sc;
#pragma unroll
        for (int z = 0; z < 4; z++) {
            ar[z] = *(const u32x4*)(ap + z * 8);
            br[z] = *(const u32x4*)(bp + z * 8);
        }
    }

#pragma unroll 1
    for (int ks = 0; ks < 1024; ks += 128) {
        __syncthreads();
#pragma unroll
        for (int z = 0; z < 4; z++) {
            *(u32x4*)&As[srow][sc + z * 8] = ar[z];
            *(u32x4*)&Bs[srow][sc + z * 8] = br[z];
        }
        __syncthreads();

        if (ks + 128 < 1024) {
            const unsigned short* ap = A + (long)(m0 + srow) * 1024 + ks + 128 + sc;
            const unsigned short* bp = Bw + (long)(n0 + srow) * 1024 + ks + 128 + sc;
#pragma unroll
            for (int z = 0; z < 4; z++) {
                ar[z] = *(const u32x4*)(ap + z * 8);
                br[z] = *(const u32x4*)(bp + z * 8);
            }
        }

#pragma unroll
        for (int kk = 0; kk < 4; kk++) {
            bf16x8 af0 = *(const bf16x8*)&As[wm * 32 + ln][kk * 32 + quad * 8];
            bf16x8 af1 = *(const bf16x8*)&As[wm * 32 + 16 + ln][kk * 32 + quad * 8];
            bf16x8 bf0 = *(const bf16x8*)&Bs[wn * 32 + ln][kk * 32 + quad * 8];
            bf16x8 bf1 = *(const bf16x8*)&Bs[wn * 32 + 16 + ln][kk * 32 + quad * 8];
            acc[0][0] = __builtin_amdgcn_mfma_f32_16x16x32_bf16(af0, bf0, acc[0][0], 0, 0, 0);
            acc[0][1] = __builtin_amdgcn_mfma_f32_16x16x32_bf16(af0, bf1, acc[0][1], 0, 0, 0);
            acc[1][0] = __builtin_amdgcn_mfma_f32_16x16x32_bf16(af1, bf0, acc[1][0], 0, 0, 0);
            acc[1][1] = __builtin_amdgcn_mfma_f32_16x16x32_bf16(af1, bf1, acc[1][1], 0, 0, 0);
        }
    }

#pragma unroll
    for (int nt = 0; nt < 2; nt++) {
        int col = n0 + wn * 32 + nt * 16 + ln;
        float bz = bias[col];
#pragma unroll
        for (int mt = 0; mt < 2; mt++)
#pragma unroll
            for (int r = 0; r < 4; r++) {
                int row = m0 + wm * 32 + mt * 16 + quad * 4 + r;
                out[(long)row * 1024 + col] = acc[mt][nt][r] + bz;
            }
    }
}

extern "C" void kernel_launch(void* const* d_in, const int* in_sizes, int n_in,
                              void* d_out, int out_size, void* d_ws, size_t ws_size,
                              hipStream_t stream) {
    const float* q    = (const float*)d_in[0];
    const float* k    = (const float*)d_in[1];
    const float* v    = (const float*)d_in[2];
    const float* Wo_w = (const float*)d_in[3];
    const float* Wo_b = (const float*)d_in[4];
    float* out = (float*)d_out;

    unsigned short* wob  = (unsigned short*)d_ws;            // [1024][1024]   2 MB
    unsigned short* kbb  = wob + (size_t)1024 * 1024;        // [32][2048][64] 8.4 MB
    unsigned short* vtb  = kbb + (size_t)32 * 2048 * 64;     // [32][64][2048] 8.4 MB
    unsigned short* pbuf = vtb + (size_t)32 * 64 * 2048;     // [2048][64][64] 16.8 MB
    float*          lbuf = (float*)(pbuf + (size_t)2048 * 4096); // [2048][64] 0.5 MB
    // ctx aliases kbb (dead after attn_k; merge_k runs after attn_k on stream)
    unsigned short* ctx  = kbb;                              // [4096][1024]   8 MB

    prep_k<<<3072, 256, 0, stream>>>(k, v, Wo_w, kbb, vtb, wob);
    attn_k<<<2048, 256, 0, stream>>>(q, kbb, vtb, pbuf, lbuf);
    merge_k<<<1024, 256, 0, stream>>>(pbuf, lbuf, ctx);
    proj_k<<<1024, 256, 0, stream>>>(ctx, wob, Wo_b, out);
}